// Round 14
// baseline (83.403 us; speedup 1.0000x reference)
//
#include <hip/hip_runtime.h>
#include <hip/hip_fp16.h>

typedef _Float16 f16x8 __attribute__((ext_vector_type(8)));
typedef _Float16 f16x4 __attribute__((ext_vector_type(4)));
typedef _Float16 f16x2 __attribute__((ext_vector_type(2)));
typedef float    f32x4 __attribute__((ext_vector_type(4)));

#define BM 32     // 32-row block tile -> 38.4 KB LDS -> 3 blocks/CU -> 6 waves/SIMD

// layer geometry (h=0 => only first IN rows of each weight matter; the
// padded K range includes a bias row at k==IN carrying 1.0 in activations)
#define IN0 74
#define H0  269
#define H1  179
#define H2  64
#define KS0 3     // ceil((IN0+1)/32)
#define KS1 9     // ceil((H0+1)/32)
#define KS2 6     // ceil((H1+1)/32)
#define NP0 272
#define NP1 192
#define NP2 64
#define PX  104   // LDS row pitches (halfs): 16B-granule stride odd mod 8 -> 2-way max
#define PH0 296
#define PH1 200

// SWAPPED operands: weights as the A-matrix, activations as B.
// C/D layout: col(lane&15)=batch row, row(lg*4+q)=feature -> each lane's 4
// outputs are 4 CONSECUTIVE features of one batch row.
#define MFMA16(a, b, c) __builtin_amdgcn_mfma_f32_16x16x32_f16(a, b, c, 0, 0, 0)

// THREE matrices per layer: m0 = 2*log2e*mask*Wf1 (+bias row), m1 = same for
// Wf2, m2 = log2e*(Wtb - Wta) (+ log2e*(btb-bta)). log2e folded at pack time
// so the epilogue uses raw v_exp_f32 (exp2) with no per-output multiply:
// tanh(f) = 1 - 2*r, r = 1/(1+exp2(acc)); ti = sigmoid(tb-ta) = 1/(1+exp2(-acc2)).
__device__ __forceinline__ float rform2(float y) {
  return __builtin_amdgcn_rcpf(1.f + exp2f(y));
}

// One CfC layer for this block's 32 rows. 8 waves iterate flat work-units
// u = (feature tile t = u/G, row-group u%G of S*16 rows). Per unit ONE
// K-sweep with 3 matrices accumulating (acc[3][S], S=2 -> 24 AGPRs): each
// LDS act-read feeds 3 MFMAs. B loads are JUST-IN-TIME inside a FORCIBLY
// ROLLED (#pragma unroll 1) ks loop — no register prefetch window, so the
// whole live set (~72 unified) fits the 85-reg/wave budget that 6 waves/SIMD
// (__launch_bounds__(512,6)) demands; the ~200cy L2 latency is hidden by
// 5 other resident waves plus cross-block desync (3 blocks/CU).
template<int KS, int NP, int HID, int IPITCH, int OPITCH, bool LAST, int S, int G>
__device__ __forceinline__ void layer_run(
    const _Float16* in_lds, _Float16* out_lds, float* out_g,
    const _Float16* __restrict__ wt, int lane, int wid)
{
  constexpr int NT = NP / 16;
  const int l15 = lane & 15;
  const int lg  = lane >> 4;
  #pragma unroll 1
  for (int u = wid; u < NT * G; u += 8) {
    const int t     = u / G;
    const int mbase = (u % G) * (S * 16);
    const _Float16* a_base = in_lds + (mbase + l15) * IPITCH + lg * 8;
    const _Float16* wtt = wt + (size_t)(t * KS * 3) * 512 + lane * 8;

    f32x4 acc[3][S] = {};
    #pragma unroll 1
    for (int ks = 0; ks < KS; ++ks) {
      const _Float16* wk = wtt + (size_t)ks * 1536;
      f16x8 b0 = *(const f16x8*)(wk);
      f16x8 b1 = *(const f16x8*)(wk + 512);
      f16x8 b2 = *(const f16x8*)(wk + 1024);
      #pragma unroll
      for (int s = 0; s < S; ++s) {
        f16x8 a = *(const f16x8*)(a_base + s * 16 * IPITCH + ks * 32);
        acc[0][s] = MFMA16(b0, a, acc[0][s]);
        acc[1][s] = MFMA16(b1, a, acc[1][s]);
        acc[2][s] = MFMA16(b2, a, acc[2][s]);
      }
    }

    // epilogue: per s, this lane owns batch row m and 4 consecutive features
    const int nb = t * 16 + lg * 4;
    #pragma unroll
    for (int s = 0; s < S; ++s) {
      const int m = mbase + s * 16 + l15;
      float o[4];
      #pragma unroll
      for (int q = 0; q < 4; ++q) {
        float r1 = rform2(acc[0][s][q]);        // acc0 = 2*log2e*f1
        float r2 = rform2(acc[1][s][q]);        // acc1 = 2*log2e*f2
        float ti = rform2(-acc[2][s][q]);       // sigmoid(tb-ta)
        o[q] = 1.f - 2.f * (r1 - ti * (r1 - r2));
      }
      if (LAST) {
        float4 v = make_float4(o[0], o[1], o[2], o[3]);
        *(float4*)(out_g + m * 64 + nb) = v;       // NP2==H2, no guard
      } else if (nb + 4 <= HID) {
        f16x4 h = {(_Float16)o[0], (_Float16)o[1], (_Float16)o[2], (_Float16)o[3]};
        *(f16x4*)(out_lds + m * OPITCH + nb) = h;  // one b64 write
      } else {
        #pragma unroll
        for (int q = 0; q < 4; ++q)
          if (nb + q < HID) out_lds[m * OPITCH + nb + q] = (_Float16)o[q];
      }
    }
  }
}

__global__ __launch_bounds__(512, 6) void cfc_fused(
    const float* __restrict__ x,
    const _Float16* __restrict__ wt0, const _Float16* __restrict__ wt1,
    const _Float16* __restrict__ wt2,
    float* __restrict__ out)
{
  __shared__ __align__(16) _Float16 xs [BM * PX];   //  6656 B
  __shared__ __align__(16) _Float16 h0s[BM * PH0];  // 18944 B
  __shared__ __align__(16) _Float16 h1s[BM * PH1];  // 12800 B -> 38400 total
  const int tid  = threadIdx.x;
  const int lane = tid & 63;
  const int wid  = tid >> 6;
  const int m0 = blockIdx.x * BM;

  // pad columns: 1.0 at the bias slot k==IN, 0 elsewhere in [IN, KP)
  for (int i = tid; i < BM * 22; i += 512) { int r = i / 22, c = IN0 + i - r * 22; xs [r * PX  + c] = (_Float16)(c == IN0 ? 1.f : 0.f); }
  for (int i = tid; i < BM * 19; i += 512) { int r = i / 19, c = H0  + i - r * 19; h0s[r * PH0 + c] = (_Float16)(c == H0  ? 1.f : 0.f); }
  for (int i = tid; i < BM * 13; i += 512) { int r = i / 13, c = H1  + i - r * 13; h1s[r * PH1 + c] = (_Float16)(c == H1  ? 1.f : 0.f); }

  // stage x (fp32 -> fp16) into LDS, float2 loads, packed b32 LDS writes
  for (int i = tid; i < BM * 37; i += 512) {
    int r = i / 37, p = i - r * 37;
    float2 v = ((const float2*)x)[(size_t)(m0 + r) * 37 + p];
    f16x2 hv = {(_Float16)v.x, (_Float16)v.y};
    *(f16x2*)(xs + r * PX + 2 * p) = hv;
  }
  __syncthreads();

  layer_run<KS0, NP0, H0, PX,  PH0, false, 2, 1>(xs,  h0s, nullptr, wt0, lane, wid);
  __syncthreads();
  layer_run<KS1, NP1, H1, PH0, PH1, false, 2, 1>(h0s, h1s, nullptr, wt1, lane, wid);
  __syncthreads();
  layer_run<KS2, NP2, H2, PH1, 1,   true,  1, 2>(h1s, nullptr, out + (size_t)m0 * 64,
                                                 wt2, lane, wid);
}

// Pack weights into fragment-major order, 3 matrices per layer.
// One thread per (chunk, lane): chunk c = (t*KS + ks)*3 + m, halfs j:
// k = ks*32+(lane>>4)*8+j, n = t*16+(lane&15).
// m=0: 2*log2e*mask*Wf1 (bias row 2*log2e*bf1); m=1: same for Wf2;
// m=2: log2e*(Wtb - Wta) (bias row log2e*(btb - bta)). Zero outside range.
__global__ void pack_w(const float* __restrict__ wf1, const float* __restrict__ wf2,
                       const float* __restrict__ wta, const float* __restrict__ wtb,
                       const float* __restrict__ bf1, const float* __restrict__ bf2,
                       const float* __restrict__ bta, const float* __restrict__ btb,
                       const int* __restrict__ mask, _Float16* __restrict__ wt,
                       int IN, int HID, int KS, int NT)
{
  const float SC2 = 2.885390081777927f;   // 2*log2(e)
  const float SC1 = 1.4426950408889634f;  // log2(e)
  int idx = blockIdx.x * 256 + threadIdx.x;
  int total = NT * KS * 3 * 64;
  if (idx >= total) return;
  int lane = idx & 63;
  int c = idx >> 6;          // chunk = (t*KS + ks)*3 + m
  int m = c % 3;
  int tk = c / 3;
  int ks = tk % KS;
  int t  = tk / KS;
  int n  = t * 16 + (lane & 15);
  int k0 = ks * 32 + (lane >> 4) * 8;
  f16x8 v = {};
  if (n < HID) {
    #pragma unroll
    for (int j = 0; j < 8; ++j) {
      int k = k0 + j;
      float f = 0.f;
      if (k < IN) {
        if (m == 0)      f = SC2 * wf1[k * HID + n] * (float)mask[k * HID + n];
        else if (m == 1) f = SC2 * wf2[k * HID + n] * (float)mask[k * HID + n];
        else             f = SC1 * (wtb[k * HID + n] - wta[k * HID + n]);
      } else if (k == IN) {
        if (m == 0)      f = SC2 * bf1[n];
        else if (m == 1) f = SC2 * bf2[n];
        else             f = SC1 * (btb[n] - bta[n]);
      }
      v[j] = (_Float16)f;
    }
  }
  *(f16x8*)(wt + (size_t)idx * 8) = v;
}

extern "C" void kernel_launch(void* const* d_in, const int* in_sizes, int n_in,
                              void* d_out, int out_size, void* d_ws, size_t ws_size,
                              hipStream_t stream)
{
  const float* x = (const float*)d_in[0];
  const float* Wf1_0 = (const float*)d_in[1];
  const float* bf1_0 = (const float*)d_in[2];
  const float* Wf2_0 = (const float*)d_in[3];
  const float* bf2_0 = (const float*)d_in[4];
  const float* Wta_0 = (const float*)d_in[5];
  const float* bta_0 = (const float*)d_in[6];
  const float* Wtb_0 = (const float*)d_in[7];
  const float* btb_0 = (const float*)d_in[8];
  const int*   msk_0 = (const int*)  d_in[9];
  const float* Wf1_1 = (const float*)d_in[10];
  const float* bf1_1 = (const float*)d_in[11];
  const float* Wf2_1 = (const float*)d_in[12];
  const float* bf2_1 = (const float*)d_in[13];
  const float* Wta_1 = (const float*)d_in[14];
  const float* bta_1 = (const float*)d_in[15];
  const float* Wtb_1 = (const float*)d_in[16];
  const float* btb_1 = (const float*)d_in[17];
  const int*   msk_1 = (const int*)  d_in[18];
  const float* Wf1_2 = (const float*)d_in[19];
  const float* bf1_2 = (const float*)d_in[20];
  const float* Wf2_2 = (const float*)d_in[21];
  const float* bf2_2 = (const float*)d_in[22];
  const float* Wta_2 = (const float*)d_in[23];
  const float* bta_2 = (const float*)d_in[24];
  const float* Wtb_2 = (const float*)d_in[25];
  const float* btb_2 = (const float*)d_in[26];
  const int*   msk_2 = (const int*)  d_in[27];

  char* ws = (char*)d_ws;
  _Float16* wt0 = (_Float16*)(ws + 0);        // 17*3*3*1024 = 156672
  _Float16* wt1 = (_Float16*)(ws + 156672);   // 12*9*3*1024 = 331776
  _Float16* wt2 = (_Float16*)(ws + 488448);   //  4*6*3*1024 =  73728

  pack_w<<<(17 * KS0 * 3 * 64 + 255) / 256, 256, 0, stream>>>(
      Wf1_0, Wf2_0, Wta_0, Wtb_0, bf1_0, bf2_0, bta_0, btb_0, msk_0, wt0, IN0, H0, KS0, 17);
  pack_w<<<(12 * KS1 * 3 * 64 + 255) / 256, 256, 0, stream>>>(
      Wf1_1, Wf2_1, Wta_1, Wtb_1, bf1_1, bf2_1, bta_1, btb_1, msk_1, wt1, H0, H1, KS1, 12);
  pack_w<<<( 4 * KS2 * 3 * 64 + 255) / 256, 256, 0, stream>>>(
      Wf1_2, Wf2_2, Wta_2, Wtb_2, bf1_2, bf2_2, bta_2, btb_2, msk_2, wt2, H1, H2, KS2, 4);

  cfc_fused<<<65536 / BM, 512, 0, stream>>>(x, wt0, wt1, wt2, (float*)d_out);
}

// Round 15
// 79.558 us; speedup vs baseline: 1.0483x; 1.0483x over previous
//
#include <hip/hip_runtime.h>
#include <hip/hip_fp16.h>

typedef _Float16 f16x8 __attribute__((ext_vector_type(8)));
typedef _Float16 f16x4 __attribute__((ext_vector_type(4)));
typedef _Float16 f16x2 __attribute__((ext_vector_type(2)));
typedef float    f32x4 __attribute__((ext_vector_type(4)));

#define BM 64     // 64-row block tile -> 76.8 KB LDS -> 2 blocks/CU, 4 waves/SIMD

// layer geometry (h=0 => only first IN rows of each weight matter; the
// padded K range includes a bias row at k==IN carrying 1.0 in activations)
#define IN0 74
#define H0  269
#define H1  179
#define H2  64
#define KS0 3     // ceil((IN0+1)/32)
#define KS1 9     // ceil((H0+1)/32)
#define KS2 6     // ceil((H1+1)/32)
#define NP0 272
#define NP1 192
#define NP2 64
#define PX  104   // LDS row pitches (halfs): dword-stride mod 32 in {4,20} ->
#define PH0 296   // the wave's 256-dword b128 read tiles all 32 banks 8-deep
#define PH1 200

// SWAPPED operands: weights as the A-matrix, activations as B.
// C/D layout: col(lane&15)=batch row, row(lg*4+q)=feature -> each lane's 4
// outputs are 4 CONSECUTIVE features of one batch row.
#define MFMA16(a, b, c) __builtin_amdgcn_mfma_f32_16x16x32_f16(a, b, c, 0, 0, 0)

// THREE matrices per layer: m0 = 2*log2e*mask*Wf1 (+bias row), m1 = same for
// Wf2, m2 = log2e*(Wtb-Wta) (+bias). log2e folded at pack time so the
// epilogue uses raw exp2: tanh(f) = 1-2r, r = 1/(1+exp2(acc));
// ti = sigmoid(tb-ta) = 1/(1+exp2(-acc2)).
__device__ __forceinline__ float rform2(float y) {
  return __builtin_amdgcn_rcpf(1.f + exp2f(y));
}

// One CfC layer for this block's 64 rows. 8 waves iterate flat work-units
// u = (feature tile t = u/G, row-group u%G of S*16 rows). Per unit ONE
// K-sweep, 3 matrices accumulating (acc[3][S] AGPRs). BOTH operand streams
// are rolling-prefetched with no net register cost beyond persistence:
//   - B (weights): classic 1-ahead window (n0-n2 loaded at loop top),
//   - A (activations): IN-PLACE reload — a[s] is overwritten with the ks+1
//     fragment immediately after its 3 MFMAs issue, so the ds_read latency
//     hides under the remaining MFMAs + next b-rotation instead of being
//     exposed at each ks boundary (the r12 structure's ~120cy/ks stall).
// ks loop FORCIBLY ROLLED (#pragma unroll 1) to stop LLVM re-hoisting all
// loads (register blowup of rounds 3/4/6/7). Live set ~100 regs < 128.
template<int KS, int NP, int HID, int IPITCH, int OPITCH, bool LAST, int S, int G>
__device__ __forceinline__ void layer_run(
    const _Float16* in_lds, _Float16* out_lds, float* out_g,
    const _Float16* __restrict__ wt, int lane, int wid)
{
  constexpr int NT = NP / 16;
  const int l15 = lane & 15;
  const int lg  = lane >> 4;
  #pragma unroll 1
  for (int u = wid; u < NT * G; u += 8) {
    const int t     = u / G;
    const int mbase = (u % G) * (S * 16);
    const _Float16* a_base = in_lds + (mbase + l15) * IPITCH + lg * 8;
    const _Float16* wtt = wt + (size_t)(t * KS * 3) * 512 + lane * 8;

    f32x4 acc[3][S] = {};
    f16x8 a[S];
    #pragma unroll
    for (int s = 0; s < S; ++s)
      a[s] = *(const f16x8*)(a_base + s * 16 * IPITCH);
    f16x8 b0 = *(const f16x8*)(wtt);
    f16x8 b1 = *(const f16x8*)(wtt + 512);
    f16x8 b2 = *(const f16x8*)(wtt + 1024);
    #pragma unroll 1
    for (int ks = 0; ks < KS - 1; ++ks) {
      const _Float16* wn = wtt + (size_t)(ks + 1) * 1536;
      f16x8 n0 = *(const f16x8*)(wn);
      f16x8 n1 = *(const f16x8*)(wn + 512);
      f16x8 n2 = *(const f16x8*)(wn + 1024);
      #pragma unroll
      for (int s = 0; s < S; ++s) {
        acc[0][s] = MFMA16(b0, a[s], acc[0][s]);
        acc[1][s] = MFMA16(b1, a[s], acc[1][s]);
        acc[2][s] = MFMA16(b2, a[s], acc[2][s]);
        a[s] = *(const f16x8*)(a_base + s * 16 * IPITCH + (ks + 1) * 32);
      }
      b0 = n0; b1 = n1; b2 = n2;
    }
    #pragma unroll
    for (int s = 0; s < S; ++s) {
      acc[0][s] = MFMA16(b0, a[s], acc[0][s]);
      acc[1][s] = MFMA16(b1, a[s], acc[1][s]);
      acc[2][s] = MFMA16(b2, a[s], acc[2][s]);
    }

    // epilogue: per s, this lane owns batch row m and 4 consecutive features
    const int nb = t * 16 + lg * 4;
    #pragma unroll
    for (int s = 0; s < S; ++s) {
      const int m = mbase + s * 16 + l15;
      float o[4];
      #pragma unroll
      for (int q = 0; q < 4; ++q) {
        float r1 = rform2(acc[0][s][q]);        // acc0 = 2*log2e*f1
        float r2 = rform2(acc[1][s][q]);        // acc1 = 2*log2e*f2
        float ti = rform2(-acc[2][s][q]);       // sigmoid(tb-ta)
        o[q] = 1.f - 2.f * (r1 - ti * (r1 - r2));
      }
      if (LAST) {
        float4 v = make_float4(o[0], o[1], o[2], o[3]);
        *(float4*)(out_g + m * 64 + nb) = v;       // NP2==H2, no guard
      } else if (nb + 4 <= HID) {
        f16x4 h = {(_Float16)o[0], (_Float16)o[1], (_Float16)o[2], (_Float16)o[3]};
        *(f16x4*)(out_lds + m * OPITCH + nb) = h;  // one b64 write
      } else {
        #pragma unroll
        for (int q = 0; q < 4; ++q)
          if (nb + q < HID) out_lds[m * OPITCH + nb + q] = (_Float16)o[q];
      }
    }
  }
}

__global__ __launch_bounds__(512, 4) void cfc_fused(
    const float* __restrict__ x,
    const _Float16* __restrict__ wt0, const _Float16* __restrict__ wt1,
    const _Float16* __restrict__ wt2,
    float* __restrict__ out)
{
  __shared__ __align__(16) _Float16 xs [BM * PX];   // 13312 B
  __shared__ __align__(16) _Float16 h0s[BM * PH0];  // 37888 B
  __shared__ __align__(16) _Float16 h1s[BM * PH1];  // 25600 B  -> 76800 total
  const int tid  = threadIdx.x;
  const int lane = tid & 63;
  const int wid  = tid >> 6;
  const int m0 = blockIdx.x * BM;

  // pad columns: 1.0 at the bias slot k==IN, 0 elsewhere in [IN, KP)
  for (int i = tid; i < BM * 22; i += 512) { int r = i / 22, c = IN0 + i - r * 22; xs [r * PX  + c] = (_Float16)(c == IN0 ? 1.f : 0.f); }
  for (int i = tid; i < BM * 19; i += 512) { int r = i / 19, c = H0  + i - r * 19; h0s[r * PH0 + c] = (_Float16)(c == H0  ? 1.f : 0.f); }
  for (int i = tid; i < BM * 13; i += 512) { int r = i / 13, c = H1  + i - r * 13; h1s[r * PH1 + c] = (_Float16)(c == H1  ? 1.f : 0.f); }

  // stage x (fp32 -> fp16) into LDS, float2 loads, packed b32 LDS writes
  for (int i = tid; i < BM * 37; i += 512) {
    int r = i / 37, p = i - r * 37;
    float2 v = ((const float2*)x)[(size_t)(m0 + r) * 37 + p];
    f16x2 hv = {(_Float16)v.x, (_Float16)v.y};
    *(f16x2*)(xs + r * PX + 2 * p) = hv;
  }
  __syncthreads();

  layer_run<KS0, NP0, H0, PX,  PH0, false, 4, 1>(xs,  h0s, nullptr, wt0, lane, wid);
  __syncthreads();
  layer_run<KS1, NP1, H1, PH0, PH1, false, 4, 1>(h0s, h1s, nullptr, wt1, lane, wid);
  __syncthreads();
  layer_run<KS2, NP2, H2, PH1, 1,   true,  2, 2>(h1s, nullptr, out + (size_t)m0 * 64,
                                                 wt2, lane, wid);
}

// Pack weights into fragment-major order, 3 matrices per layer.
// One thread per (chunk, lane): chunk c = (t*KS + ks)*3 + m, halfs j:
// k = ks*32+(lane>>4)*8+j, n = t*16+(lane&15).
// m=0: 2*log2e*mask*Wf1 (bias row 2*log2e*bf1); m=1: same for Wf2;
// m=2: log2e*(Wtb - Wta) (bias row log2e*(btb - bta)). Zero outside range.
__global__ void pack_w(const float* __restrict__ wf1, const float* __restrict__ wf2,
                       const float* __restrict__ wta, const float* __restrict__ wtb,
                       const float* __restrict__ bf1, const float* __restrict__ bf2,
                       const float* __restrict__ bta, const float* __restrict__ btb,
                       const int* __restrict__ mask, _Float16* __restrict__ wt,
                       int IN, int HID, int KS, int NT)
{
  const float SC2 = 2.885390081777927f;   // 2*log2(e)
  const float SC1 = 1.4426950408889634f;  // log2(e)
  int idx = blockIdx.x * 256 + threadIdx.x;
  int total = NT * KS * 3 * 64;
  if (idx >= total) return;
  int lane = idx & 63;
  int c = idx >> 6;          // chunk = (t*KS + ks)*3 + m
  int m = c % 3;
  int tk = c / 3;
  int ks = tk % KS;
  int t  = tk / KS;
  int n  = t * 16 + (lane & 15);
  int k0 = ks * 32 + (lane >> 4) * 8;
  f16x8 v = {};
  if (n < HID) {
    #pragma unroll
    for (int j = 0; j < 8; ++j) {
      int k = k0 + j;
      float f = 0.f;
      if (k < IN) {
        if (m == 0)      f = SC2 * wf1[k * HID + n] * (float)mask[k * HID + n];
        else if (m == 1) f = SC2 * wf2[k * HID + n] * (float)mask[k * HID + n];
        else             f = SC1 * (wtb[k * HID + n] - wta[k * HID + n]);
      } else if (k == IN) {
        if (m == 0)      f = SC2 * bf1[n];
        else if (m == 1) f = SC2 * bf2[n];
        else             f = SC1 * (btb[n] - bta[n]);
      }
      v[j] = (_Float16)f;
    }
  }
  *(f16x8*)(wt + (size_t)idx * 8) = v;
}

extern "C" void kernel_launch(void* const* d_in, const int* in_sizes, int n_in,
                              void* d_out, int out_size, void* d_ws, size_t ws_size,
                              hipStream_t stream)
{
  const float* x = (const float*)d_in[0];
  const float* Wf1_0 = (const float*)d_in[1];
  const float* bf1_0 = (const float*)d_in[2];
  const float* Wf2_0 = (const float*)d_in[3];
  const float* bf2_0 = (const float*)d_in[4];
  const float* Wta_0 = (const float*)d_in[5];
  const float* bta_0 = (const float*)d_in[6];
  const float* Wtb_0 = (const float*)d_in[7];
  const float* btb_0 = (const float*)d_in[8];
  const int*   msk_0 = (const int*)  d_in[9];
  const float* Wf1_1 = (const float*)d_in[10];
  const float* bf1_1 = (const float*)d_in[11];
  const float* Wf2_1 = (const float*)d_in[12];
  const float* bf2_1 = (const float*)d_in[13];
  const float* Wta_1 = (const float*)d_in[14];
  const float* bta_1 = (const float*)d_in[15];
  const float* Wtb_1 = (const float*)d_in[16];
  const float* btb_1 = (const float*)d_in[17];
  const int*   msk_1 = (const int*)  d_in[18];
  const float* Wf1_2 = (const float*)d_in[19];
  const float* bf1_2 = (const float*)d_in[20];
  const float* Wf2_2 = (const float*)d_in[21];
  const float* bf2_2 = (const float*)d_in[22];
  const float* Wta_2 = (const float*)d_in[23];
  const float* bta_2 = (const float*)d_in[24];
  const float* Wtb_2 = (const float*)d_in[25];
  const float* btb_2 = (const float*)d_in[26];
  const int*   msk_2 = (const int*)  d_in[27];

  char* ws = (char*)d_ws;
  _Float16* wt0 = (_Float16*)(ws + 0);        // 17*3*3*1024 = 156672
  _Float16* wt1 = (_Float16*)(ws + 156672);   // 12*9*3*1024 = 331776
  _Float16* wt2 = (_Float16*)(ws + 488448);   //  4*6*3*1024 =  73728

  pack_w<<<(17 * KS0 * 3 * 64 + 255) / 256, 256, 0, stream>>>(
      Wf1_0, Wf2_0, Wta_0, Wtb_0, bf1_0, bf2_0, bta_0, btb_0, msk_0, wt0, IN0, H0, KS0, 17);
  pack_w<<<(12 * KS1 * 3 * 64 + 255) / 256, 256, 0, stream>>>(
      Wf1_1, Wf2_1, Wta_1, Wtb_1, bf1_1, bf2_1, bta_1, btb_1, msk_1, wt1, H0, H1, KS1, 12);
  pack_w<<<( 4 * KS2 * 3 * 64 + 255) / 256, 256, 0, stream>>>(
      Wf1_2, Wf2_2, Wta_2, Wtb_2, bf1_2, bf2_2, bta_2, btb_2, msk_2, wt2, H1, H2, KS2, 4);

  cfc_fused<<<65536 / BM, 512, 0, stream>>>(x, wt0, wt1, wt2, (float*)d_out);
}